// Round 1
// baseline (577.233 us; speedup 1.0000x reference)
//
#include <hip/hip_runtime.h>

#define N_NODES 10000
#define N_EDGES 160000
#define IN_DIM 512
#define HID 128
#define OUT_DIM 64

// ---------------------------------------------------------------------------
// Tiled fp32 GEMM: C[M,N] = A[M,K] * B[N,K]^T   (both row-major, NT form)
// 256 threads, BM=BN=64, BK=32, 4x4 micro-tile per thread.
// ---------------------------------------------------------------------------
template <int BM, int BN, int BK>
__global__ __launch_bounds__(256) void gemm_nt(const float* __restrict__ A,
                                               const float* __restrict__ B,
                                               float* __restrict__ C,
                                               int M, int N, int K) {
    __shared__ float As[BK][BM + 1];
    __shared__ float Bs[BK][BN + 1];

    const int t  = threadIdx.x;
    const int m0 = blockIdx.y * BM;
    const int n0 = blockIdx.x * BN;
    const int ty = t >> 4;          // 0..15
    const int tx = t & 15;          // 0..15

    float acc[4][4] = {};

    for (int k0 = 0; k0 < K; k0 += BK) {
        // Load A tile (BM x BK) as float4, store transposed into As[k][m]
        #pragma unroll
        for (int i = t; i < BM * BK / 4; i += 256) {
            int row = i / (BK / 4);
            int c4  = (i % (BK / 4)) * 4;
            int m   = m0 + row;
            float4 v = make_float4(0.f, 0.f, 0.f, 0.f);
            if (m < M)
                v = *reinterpret_cast<const float4*>(&A[(size_t)m * K + k0 + c4]);
            As[c4 + 0][row] = v.x;
            As[c4 + 1][row] = v.y;
            As[c4 + 2][row] = v.z;
            As[c4 + 3][row] = v.w;
        }
        // Load B tile (BN x BK)
        #pragma unroll
        for (int i = t; i < BN * BK / 4; i += 256) {
            int row = i / (BK / 4);
            int c4  = (i % (BK / 4)) * 4;
            int n   = n0 + row;
            float4 v = make_float4(0.f, 0.f, 0.f, 0.f);
            if (n < N)
                v = *reinterpret_cast<const float4*>(&B[(size_t)n * K + k0 + c4]);
            Bs[c4 + 0][row] = v.x;
            Bs[c4 + 1][row] = v.y;
            Bs[c4 + 2][row] = v.z;
            Bs[c4 + 3][row] = v.w;
        }
        __syncthreads();

        #pragma unroll
        for (int k = 0; k < BK; ++k) {
            float a[4], b[4];
            #pragma unroll
            for (int i = 0; i < 4; ++i) a[i] = As[k][ty * 4 + i];
            #pragma unroll
            for (int j = 0; j < 4; ++j) b[j] = Bs[k][tx * 4 + j];
            #pragma unroll
            for (int i = 0; i < 4; ++i)
                #pragma unroll
                for (int j = 0; j < 4; ++j)
                    acc[i][j] = fmaf(a[i], b[j], acc[i][j]);
        }
        __syncthreads();
    }

    #pragma unroll
    for (int i = 0; i < 4; ++i) {
        int m = m0 + ty * 4 + i;
        if (m >= M) continue;
        #pragma unroll
        for (int j = 0; j < 4; ++j) {
            int n = n0 + tx * 4 + j;
            if (n < N) C[(size_t)m * N + n] = acc[i][j];
        }
    }
}

// ---------------------------------------------------------------------------
// In-degree count (float so downstream division is direct)
// ---------------------------------------------------------------------------
__global__ void count_edges(const int* __restrict__ dst, float* __restrict__ cnt) {
    int e = blockIdx.x * blockDim.x + threadIdx.x;
    if (e < N_EDGES) atomicAdd(&cnt[dst[e]], 1.0f);
}

// ---------------------------------------------------------------------------
// Scatter-add: agg[dst[e]] += V[src[e]]  over D features.
// D/4 threads per edge, float4 loads, scalar f32 atomics.
// ---------------------------------------------------------------------------
template <int D>
__global__ void scatter_add(const float* __restrict__ V,
                            const int* __restrict__ src,
                            const int* __restrict__ dst,
                            float* __restrict__ agg) {
    constexpr int TPE = D / 4;  // threads per edge
    long long tid = (long long)blockIdx.x * blockDim.x + threadIdx.x;
    int e = (int)(tid / TPE);
    if (e >= N_EDGES) return;
    int f = (int)(tid % TPE) * 4;

    int s = src[e];
    int d = dst[e];
    float4 v = *reinterpret_cast<const float4*>(&V[(size_t)s * D + f]);
    float* p = &agg[(size_t)d * D + f];
    atomicAdd(p + 0, v.x);
    atomicAdd(p + 1, v.y);
    atomicAdd(p + 2, v.z);
    atomicAdd(p + 3, v.w);
}

// ---------------------------------------------------------------------------
// h = relu(agg/max(cnt,1) + xr + b)   (elementwise over N_NODES x D)
// ---------------------------------------------------------------------------
template <int D, bool RELU>
__global__ void combine(const float* __restrict__ agg,
                        const float* __restrict__ xr,
                        const float* __restrict__ b,
                        const float* __restrict__ cnt,
                        float* __restrict__ out) {
    int i = blockIdx.x * blockDim.x + threadIdx.x;
    if (i >= N_NODES * D) return;
    int node = i / D;
    int j = i % D;
    float inv = 1.0f / fmaxf(cnt[node], 1.0f);
    float v = agg[i] * inv + xr[i] + b[j];
    if (RELU) v = fmaxf(v, 0.0f);
    out[i] = v;
}

// ---------------------------------------------------------------------------
extern "C" void kernel_launch(void* const* d_in, const int* in_sizes, int n_in,
                              void* d_out, int out_size, void* d_ws, size_t ws_size,
                              hipStream_t stream) {
    const float* x   = (const float*)d_in[0];
    const int*   ei  = (const int*)d_in[1];
    const int*   src = ei;            // edge_index[0]
    const int*   dst = ei + N_EDGES;  // edge_index[1]
    const float* W1l = (const float*)d_in[2];
    const float* W1r = (const float*)d_in[3];
    const float* b1  = (const float*)d_in[4];
    const float* W2l = (const float*)d_in[5];
    const float* W2r = (const float*)d_in[6];
    const float* b2  = (const float*)d_in[7];
    float*       out = (float*)d_out;

    // Workspace layout (floats). Zeroed region first (AGG1|AGG2|cnt).
    float* ws   = (float*)d_ws;
    float* AGG1 = ws;                                   // N*HID
    float* AGG2 = AGG1 + (size_t)N_NODES * HID;         // N*OUT
    float* cnt  = AGG2 + (size_t)N_NODES * OUT_DIM;     // N
    float* XL   = cnt + N_NODES;                        // N*HID
    float* XR   = XL + (size_t)N_NODES * HID;           // N*HID (becomes h)
    float* HL   = XR + (size_t)N_NODES * HID;           // N*OUT
    float* HR   = HL + (size_t)N_NODES * OUT_DIM;       // N*OUT

    size_t zero_bytes =
        ((size_t)N_NODES * HID + (size_t)N_NODES * OUT_DIM + N_NODES) * sizeof(float);
    hipMemsetAsync(d_ws, 0, zero_bytes, stream);

    // in-degree counts
    count_edges<<<(N_EDGES + 255) / 256, 256, 0, stream>>>(dst, cnt);

    // Layer 1 projections: XL = x@W1_l.T, XR = x@W1_r.T
    {
        dim3 grid(HID / 64, (N_NODES + 63) / 64);
        gemm_nt<64, 64, 32><<<grid, 256, 0, stream>>>(x, W1l, XL, N_NODES, HID, IN_DIM);
        gemm_nt<64, 64, 32><<<grid, 256, 0, stream>>>(x, W1r, XR, N_NODES, HID, IN_DIM);
    }

    // AGG1[dst] += XL[src]
    {
        long long total = (long long)N_EDGES * (HID / 4);
        scatter_add<HID><<<(int)((total + 255) / 256), 256, 0, stream>>>(XL, src, dst, AGG1);
    }

    // h = relu(AGG1/cnt + XR + b1), in place over XR
    combine<HID, true><<<(N_NODES * HID + 255) / 256, 256, 0, stream>>>(AGG1, XR, b1, cnt, XR);

    // Layer 2 projections: HL = h@W2_l.T, HR = h@W2_r.T
    {
        dim3 grid(OUT_DIM / 64, (N_NODES + 63) / 64);
        gemm_nt<64, 64, 32><<<grid, 256, 0, stream>>>(XR, W2l, HL, N_NODES, OUT_DIM, HID);
        gemm_nt<64, 64, 32><<<grid, 256, 0, stream>>>(XR, W2r, HR, N_NODES, OUT_DIM, HID);
    }

    // AGG2[dst] += HL[src]
    {
        long long total = (long long)N_EDGES * (OUT_DIM / 4);
        scatter_add<OUT_DIM><<<(int)((total + 255) / 256), 256, 0, stream>>>(HL, src, dst, AGG2);
    }

    // out = AGG2/cnt + HR + b2
    combine<OUT_DIM, false><<<(N_NODES * OUT_DIM + 255) / 256, 256, 0, stream>>>(AGG2, HR, b2, cnt, out);
}

// Round 2
// 231.975 us; speedup vs baseline: 2.4883x; 2.4883x over previous
//
#include <hip/hip_runtime.h>

#define N_NODES 10000
#define N_EDGES 160000
#define IN_DIM 512
#define HID 128
#define OUT_DIM 64

// ---------------------------------------------------------------------------
// Tiled fp32 GEMM: C[M,N] = A[M,K] * B[N,K]^T   (both row-major, NT form)
// 256 threads, BM=BN=64, BK=32, 4x4 micro-tile per thread.
// ---------------------------------------------------------------------------
template <int BM, int BN, int BK>
__global__ __launch_bounds__(256) void gemm_nt(const float* __restrict__ A,
                                               const float* __restrict__ B,
                                               float* __restrict__ C,
                                               int M, int N, int K) {
    __shared__ float As[BK][BM + 1];
    __shared__ float Bs[BK][BN + 1];

    const int t  = threadIdx.x;
    const int m0 = blockIdx.y * BM;
    const int n0 = blockIdx.x * BN;
    const int ty = t >> 4;          // 0..15
    const int tx = t & 15;          // 0..15

    float acc[4][4] = {};

    for (int k0 = 0; k0 < K; k0 += BK) {
        #pragma unroll
        for (int i = t; i < BM * BK / 4; i += 256) {
            int row = i / (BK / 4);
            int c4  = (i % (BK / 4)) * 4;
            int m   = m0 + row;
            float4 v = make_float4(0.f, 0.f, 0.f, 0.f);
            if (m < M)
                v = *reinterpret_cast<const float4*>(&A[(size_t)m * K + k0 + c4]);
            As[c4 + 0][row] = v.x;
            As[c4 + 1][row] = v.y;
            As[c4 + 2][row] = v.z;
            As[c4 + 3][row] = v.w;
        }
        #pragma unroll
        for (int i = t; i < BN * BK / 4; i += 256) {
            int row = i / (BK / 4);
            int c4  = (i % (BK / 4)) * 4;
            int n   = n0 + row;
            float4 v = make_float4(0.f, 0.f, 0.f, 0.f);
            if (n < N)
                v = *reinterpret_cast<const float4*>(&B[(size_t)n * K + k0 + c4]);
            Bs[c4 + 0][row] = v.x;
            Bs[c4 + 1][row] = v.y;
            Bs[c4 + 2][row] = v.z;
            Bs[c4 + 3][row] = v.w;
        }
        __syncthreads();

        #pragma unroll
        for (int k = 0; k < BK; ++k) {
            float a[4], b[4];
            #pragma unroll
            for (int i = 0; i < 4; ++i) a[i] = As[k][ty * 4 + i];
            #pragma unroll
            for (int j = 0; j < 4; ++j) b[j] = Bs[k][tx * 4 + j];
            #pragma unroll
            for (int i = 0; i < 4; ++i)
                #pragma unroll
                for (int j = 0; j < 4; ++j)
                    acc[i][j] = fmaf(a[i], b[j], acc[i][j]);
        }
        __syncthreads();
    }

    #pragma unroll
    for (int i = 0; i < 4; ++i) {
        int m = m0 + ty * 4 + i;
        if (m >= M) continue;
        #pragma unroll
        for (int j = 0; j < 4; ++j) {
            int n = n0 + tx * 4 + j;
            if (n < N) C[(size_t)m * N + n] = acc[i][j];
        }
    }
}

// ---------------------------------------------------------------------------
// CSR build: histogram, exclusive scan, bucket fill
// ---------------------------------------------------------------------------
__global__ void count_edges(const int* __restrict__ dst, int* __restrict__ cnt) {
    int e = blockIdx.x * blockDim.x + threadIdx.x;
    if (e < N_EDGES) atomicAdd(&cnt[dst[e]], 1);
}

__global__ __launch_bounds__(1024) void scan_offsets(const int* __restrict__ cnt,
                                                     int* __restrict__ offs) {
    __shared__ int smem[1024];
    __shared__ int carry;
    if (threadIdx.x == 0) carry = 0;
    __syncthreads();
    for (int base = 0; base < N_NODES; base += 1024) {
        int i = base + threadIdx.x;
        int v = (i < N_NODES) ? cnt[i] : 0;
        smem[threadIdx.x] = v;
        __syncthreads();
        for (int d = 1; d < 1024; d <<= 1) {
            int t = (threadIdx.x >= d) ? smem[threadIdx.x - d] : 0;
            __syncthreads();
            smem[threadIdx.x] += t;
            __syncthreads();
        }
        if (i < N_NODES) offs[i] = carry + smem[threadIdx.x] - v;  // exclusive
        __syncthreads();                 // all threads have read carry
        if (threadIdx.x == 1023) carry += smem[1023];
        __syncthreads();
    }
}

__global__ void fill_buckets(const int* __restrict__ src, const int* __restrict__ dst,
                             const int* __restrict__ offs, int* __restrict__ fill,
                             int* __restrict__ bsrc) {
    int e = blockIdx.x * blockDim.x + threadIdx.x;
    if (e >= N_EDGES) return;
    int d = dst[e];
    int pos = offs[d] + atomicAdd(&fill[d], 1);
    bsrc[pos] = src[e];
}

// ---------------------------------------------------------------------------
// Fused mean-aggregate + self + bias (+relu): one wave per node.
// Lanes own D/64 feature slots; serial loop over the node's in-edges,
// reading the projected message table V (L2/L3-resident).
// ---------------------------------------------------------------------------
template <int D, bool RELU>
__global__ __launch_bounds__(256) void gather_combine(
    const float* __restrict__ V,     // projected messages [N, D]
    const float* __restrict__ xr,    // self-projection   [N, D]
    const float* __restrict__ b,     // bias [D]
    const int* __restrict__ offs,
    const int* __restrict__ cnt,
    const int* __restrict__ bsrc,
    float* __restrict__ out) {
    constexpr int LPF = D / 64;      // floats per lane
    int wave = threadIdx.x >> 6;
    int lane = threadIdx.x & 63;
    int n = blockIdx.x * 4 + wave;
    if (n >= N_NODES) return;

    int beg = offs[n];
    int deg = cnt[n];
    float acc[LPF] = {};
    for (int i = beg; i < beg + deg; ++i) {
        int s = bsrc[i];               // wave-uniform (broadcast)
        const float* p = &V[(size_t)s * D + lane * LPF];
        #pragma unroll
        for (int j = 0; j < LPF; ++j) acc[j] += p[j];
    }
    float inv = (deg > 0) ? (1.0f / (float)deg) : 0.0f;
    #pragma unroll
    for (int j = 0; j < LPF; ++j) {
        int f = lane * LPF + j;
        float v = acc[j] * inv + xr[(size_t)n * D + f] + b[f];
        if (RELU) v = fmaxf(v, 0.0f);
        out[(size_t)n * D + f] = v;
    }
}

// ---------------------------------------------------------------------------
extern "C" void kernel_launch(void* const* d_in, const int* in_sizes, int n_in,
                              void* d_out, int out_size, void* d_ws, size_t ws_size,
                              hipStream_t stream) {
    const float* x   = (const float*)d_in[0];
    const int*   ei  = (const int*)d_in[1];
    const int*   src = ei;            // edge_index[0]
    const int*   dst = ei + N_EDGES;  // edge_index[1]
    const float* W1l = (const float*)d_in[2];
    const float* W1r = (const float*)d_in[3];
    const float* b1  = (const float*)d_in[4];
    const float* W2l = (const float*)d_in[5];
    const float* W2r = (const float*)d_in[6];
    const float* b2  = (const float*)d_in[7];
    float*       out = (float*)d_out;

    // Workspace layout. Zeroed region first: cnt | fill (ints).
    int* cnt  = (int*)d_ws;                 // N
    int* fill = cnt + N_NODES;              // N
    int* offs = fill + N_NODES;             // N
    int* bsrc = offs + N_NODES;             // E
    float* XL = (float*)(bsrc + N_EDGES);   // N*HID
    float* XR = XL + (size_t)N_NODES * HID; // N*HID (becomes h input for L2)
    float* HL = XR + (size_t)N_NODES * HID; // N*OUT
    float* HR = HL + (size_t)N_NODES * OUT_DIM; // N*OUT

    hipMemsetAsync(d_ws, 0, 2 * N_NODES * sizeof(int), stream);

    // CSR build (by dst)
    count_edges<<<(N_EDGES + 255) / 256, 256, 0, stream>>>(dst, cnt);
    scan_offsets<<<1, 1024, 0, stream>>>(cnt, offs);
    fill_buckets<<<(N_EDGES + 255) / 256, 256, 0, stream>>>(src, dst, offs, fill, bsrc);

    // Layer 1 projections: XL = x@W1_l.T, XR = x@W1_r.T
    {
        dim3 grid(HID / 64, (N_NODES + 63) / 64);
        gemm_nt<64, 64, 32><<<grid, 256, 0, stream>>>(x, W1l, XL, N_NODES, HID, IN_DIM);
        gemm_nt<64, 64, 32><<<grid, 256, 0, stream>>>(x, W1r, XR, N_NODES, HID, IN_DIM);
    }

    // h = relu(mean_agg(XL) + XR + b1) -> overwrite XR
    gather_combine<HID, true><<<(N_NODES + 3) / 4, 256, 0, stream>>>(
        XL, XR, b1, offs, cnt, bsrc, XR);

    // Layer 2 projections: HL = h@W2_l.T, HR = h@W2_r.T
    {
        dim3 grid(OUT_DIM / 64, (N_NODES + 63) / 64);
        gemm_nt<64, 64, 32><<<grid, 256, 0, stream>>>(XR, W2l, HL, N_NODES, OUT_DIM, HID);
        gemm_nt<64, 64, 32><<<grid, 256, 0, stream>>>(XR, W2r, HR, N_NODES, OUT_DIM, HID);
    }

    // out = mean_agg(HL) + HR + b2
    gather_combine<OUT_DIM, false><<<(N_NODES + 3) / 4, 256, 0, stream>>>(
        HL, HR, b2, offs, cnt, bsrc, out);
}

// Round 3
// 127.412 us; speedup vs baseline: 4.5305x; 1.8207x over previous
//
#include <hip/hip_runtime.h>

#define N_NODES 10000
#define N_EDGES 160000
#define IN_DIM 512
#define HID 128
#define OUT_DIM 64

typedef __attribute__((ext_vector_type(8))) short bf16x8;
typedef __attribute__((ext_vector_type(4))) float f32x4;

__device__ inline ushort f2b(float f) {
    unsigned u = __float_as_uint(f);
    u += 0x7fff + ((u >> 16) & 1);   // round-to-nearest-even
    return (ushort)(u >> 16);
}

// ---------------------------------------------------------------------------
// One-shot fp32 -> bf16 conversion of x, W1l|W1r, W2l|W2r (float4 per thread)
// ---------------------------------------------------------------------------
#define XC   (N_NODES * IN_DIM / 4)          // 1,280,000
#define W1C  (HID * IN_DIM / 4)              // 16,384
#define W2C  (OUT_DIM * HID / 4)             // 2,048
#define SEG1 (XC)
#define SEG2 (SEG1 + W1C)
#define SEG3 (SEG2 + W1C)
#define SEG4 (SEG3 + W2C)
#define SEG5 (SEG4 + W2C)

__global__ void convert_all(const float* __restrict__ x,
                            const float* __restrict__ w1l, const float* __restrict__ w1r,
                            const float* __restrict__ w2l, const float* __restrict__ w2r,
                            ushort* __restrict__ xb, ushort* __restrict__ wc1,
                            ushort* __restrict__ wc2) {
    int i = blockIdx.x * blockDim.x + threadIdx.x;
    const float* src; ushort* dst; int off;
    if      (i < SEG1) { src = x;   dst = xb;                 off = i; }
    else if (i < SEG2) { src = w1l; dst = wc1;                off = i - SEG1; }
    else if (i < SEG3) { src = w1r; dst = wc1 + HID * IN_DIM; off = i - SEG2; }
    else if (i < SEG4) { src = w2l; dst = wc2;                off = i - SEG3; }
    else if (i < SEG5) { src = w2r; dst = wc2 + OUT_DIM * HID; off = i - SEG4; }
    else return;
    float4 v = *reinterpret_cast<const float4*>(src + (size_t)off * 4);
    ushort4 o = make_ushort4(f2b(v.x), f2b(v.y), f2b(v.z), f2b(v.w));
    *reinterpret_cast<ushort4*>(dst + (size_t)off * 4) = o;
}

// ---------------------------------------------------------------------------
// bf16 MFMA GEMM:  C[M, NT] = A[M,K] * B[NT,K]^T, split-stored into C0|C1 at
// column HALF. 256 threads = 4 waves; wave w owns rows [w*WROWS, (w+1)*WROWS)
// of the BM=4*WROWS tile, all 64 block cols. BK=32 per step.
// LDS tiles XOR-swizzled in 16B chunks: conflict-free writes & frag reads.
// ---------------------------------------------------------------------------
template <int WROWS, int K, int NT, int HALF>
__global__ __launch_bounds__(256) void gemm_mfma(const ushort* __restrict__ A,
                                                 const ushort* __restrict__ B,
                                                 float* __restrict__ C0,
                                                 float* __restrict__ C1, int M) {
    constexpr int BM = 4 * WROWS;
    constexpr int RF = WROWS / 16;
    __shared__ __align__(16) ushort Asm[BM * 32];
    __shared__ __align__(16) ushort Bsm[64 * 32];

    const int t    = threadIdx.x;
    const int lane = t & 63;
    const int w    = t >> 6;
    const int m0   = blockIdx.y * BM;
    const int n0   = blockIdx.x * 64;
    const int kch  = lane >> 4;      // k-chunk group for fragments
    const int lrow = lane & 15;

    f32x4 acc[RF][4] = {};

    for (int k0 = 0; k0 < K; k0 += 32) {
        // stage A tile (BM x 32)
        #pragma unroll
        for (int c = t; c < BM * 4; c += 256) {
            int row = c >> 2, kc = c & 3;
            int m = m0 + row;
            uint4 v = make_uint4(0u, 0u, 0u, 0u);
            if (m < M)
                v = *reinterpret_cast<const uint4*>(&A[(size_t)m * K + k0 + kc * 8]);
            *reinterpret_cast<uint4*>(&Asm[row * 32 + ((kc ^ (row & 3)) << 3)]) = v;
        }
        // stage B tile (64 x 32)
        {
            int row = t >> 2, kc = t & 3;
            uint4 v = *reinterpret_cast<const uint4*>(&B[(size_t)(n0 + row) * K + k0 + kc * 8]);
            *reinterpret_cast<uint4*>(&Bsm[row * 32 + ((kc ^ (row & 3)) << 3)]) = v;
        }
        __syncthreads();

        bf16x8 afr[RF], bfr[4];
        #pragma unroll
        for (int rf = 0; rf < RF; ++rf) {
            int row = w * WROWS + rf * 16 + lrow;
            afr[rf] = *reinterpret_cast<const bf16x8*>(&Asm[row * 32 + ((kch ^ (row & 3)) << 3)]);
        }
        #pragma unroll
        for (int cf = 0; cf < 4; ++cf) {
            int row = cf * 16 + lrow;
            bfr[cf] = *reinterpret_cast<const bf16x8*>(&Bsm[row * 32 + ((kch ^ (row & 3)) << 3)]);
        }
        #pragma unroll
        for (int rf = 0; rf < RF; ++rf)
            #pragma unroll
            for (int cf = 0; cf < 4; ++cf)
                acc[rf][cf] = __builtin_amdgcn_mfma_f32_16x16x32_bf16(
                    afr[rf], bfr[cf], acc[rf][cf], 0, 0, 0);
        __syncthreads();
    }

    // epilogue: C layout col = lane&15, row = (lane>>4)*4 + j  [m89]
    #pragma unroll
    for (int rf = 0; rf < RF; ++rf) {
        int baserow = m0 + w * WROWS + rf * 16 + (lane >> 4) * 4;
        #pragma unroll
        for (int cf = 0; cf < 4; ++cf) {
            int col = n0 + cf * 16 + lrow;
            float* Cp; int c2;
            if (col < HALF) { Cp = C0; c2 = col; }
            else            { Cp = C1; c2 = col - HALF; }
            #pragma unroll
            for (int j = 0; j < 4; ++j) {
                int row = baserow + j;
                if (row < M) Cp[(size_t)row * HALF + c2] = acc[rf][cf][j];
            }
        }
    }
}

// ---------------------------------------------------------------------------
// CSR build: histogram, exclusive scan, bucket fill
// ---------------------------------------------------------------------------
__global__ void count_edges(const int* __restrict__ dst, int* __restrict__ cnt) {
    int e = blockIdx.x * blockDim.x + threadIdx.x;
    if (e < N_EDGES) atomicAdd(&cnt[dst[e]], 1);
}

__global__ __launch_bounds__(1024) void scan_offsets(const int* __restrict__ cnt,
                                                     int* __restrict__ offs) {
    __shared__ int smem[1024];
    __shared__ int carry;
    if (threadIdx.x == 0) carry = 0;
    __syncthreads();
    for (int base = 0; base < N_NODES; base += 1024) {
        int i = base + threadIdx.x;
        int v = (i < N_NODES) ? cnt[i] : 0;
        smem[threadIdx.x] = v;
        __syncthreads();
        for (int d = 1; d < 1024; d <<= 1) {
            int t = (threadIdx.x >= d) ? smem[threadIdx.x - d] : 0;
            __syncthreads();
            smem[threadIdx.x] += t;
            __syncthreads();
        }
        if (i < N_NODES) offs[i] = carry + smem[threadIdx.x] - v;  // exclusive
        __syncthreads();
        if (threadIdx.x == 1023) carry += smem[1023];
        __syncthreads();
    }
}

__global__ void fill_buckets(const int* __restrict__ src, const int* __restrict__ dst,
                             const int* __restrict__ offs, int* __restrict__ fill,
                             int* __restrict__ bsrc) {
    int e = blockIdx.x * blockDim.x + threadIdx.x;
    if (e >= N_EDGES) return;
    int d = dst[e];
    int pos = offs[d] + atomicAdd(&fill[d], 1);
    bsrc[pos] = src[e];
}

// ---------------------------------------------------------------------------
// Fused mean-aggregate + self + bias (+relu): one wave per node.
// ---------------------------------------------------------------------------
template <int D, bool RELU, typename OT>
__global__ __launch_bounds__(256) void gather_combine(
    const float* __restrict__ V, const float* __restrict__ xr,
    const float* __restrict__ b, const int* __restrict__ offs,
    const int* __restrict__ cnt, const int* __restrict__ bsrc,
    OT* __restrict__ out) {
    constexpr int LPF = D / 64;
    int wave = threadIdx.x >> 6;
    int lane = threadIdx.x & 63;
    int n = blockIdx.x * 4 + wave;
    if (n >= N_NODES) return;

    int beg = offs[n];
    int deg = cnt[n];
    float acc[LPF] = {};
    for (int i = beg; i < beg + deg; ++i) {
        int s = bsrc[i];                      // wave-uniform
        const float* p = &V[(size_t)s * D + lane * LPF];
        #pragma unroll
        for (int j = 0; j < LPF; ++j) acc[j] += p[j];
    }
    float inv = (deg > 0) ? (1.0f / (float)deg) : 0.0f;
    #pragma unroll
    for (int j = 0; j < LPF; ++j) {
        int f = lane * LPF + j;
        float v = acc[j] * inv + xr[(size_t)n * D + f] + b[f];
        if (RELU) v = fmaxf(v, 0.0f);
        if constexpr (sizeof(OT) == 2) out[(size_t)n * D + f] = (OT)f2b(v);
        else                           out[(size_t)n * D + f] = v;
    }
}

// ---------------------------------------------------------------------------
extern "C" void kernel_launch(void* const* d_in, const int* in_sizes, int n_in,
                              void* d_out, int out_size, void* d_ws, size_t ws_size,
                              hipStream_t stream) {
    const float* x   = (const float*)d_in[0];
    const int*   ei  = (const int*)d_in[1];
    const int*   src = ei;
    const int*   dst = ei + N_EDGES;
    const float* W1l = (const float*)d_in[2];
    const float* W1r = (const float*)d_in[3];
    const float* b1  = (const float*)d_in[4];
    const float* W2l = (const float*)d_in[5];
    const float* W2r = (const float*)d_in[6];
    const float* b2  = (const float*)d_in[7];
    float*       out = (float*)d_out;

    // Workspace layout
    int* cnt  = (int*)d_ws;                       // N
    int* fill = cnt + N_NODES;                    // N
    int* offs = fill + N_NODES;                   // N
    int* bsrc = offs + N_NODES;                   // E
    ushort* xb  = (ushort*)(bsrc + N_EDGES);      // N*512 bf16 (10.24 MB region)
    ushort* wc1 = xb + (size_t)N_NODES * IN_DIM;  // 256*512 bf16
    ushort* wc2 = wc1 + (size_t)2 * HID * IN_DIM; // 128*128 bf16
    float* XL   = (float*)(wc2 + 2 * OUT_DIM * HID);  // N*128
    float* XR   = XL + (size_t)N_NODES * HID;         // N*128
    // After layer-1 gather, xb region is dead; reuse it for h/HL/HR.
    ushort* hb = xb;                                        // N*128 bf16
    float* HL  = (float*)(hb + (size_t)N_NODES * HID);      // N*64
    float* HR  = HL + (size_t)N_NODES * OUT_DIM;            // N*64

    hipMemsetAsync(d_ws, 0, 2 * N_NODES * sizeof(int), stream);

    // CSR build (by dst)
    count_edges<<<(N_EDGES + 255) / 256, 256, 0, stream>>>(dst, cnt);
    scan_offsets<<<1, 1024, 0, stream>>>(cnt, offs);
    fill_buckets<<<(N_EDGES + 255) / 256, 256, 0, stream>>>(src, dst, offs, fill, bsrc);

    // fp32 -> bf16 (x + all weights)
    convert_all<<<(SEG5 + 255) / 256, 256, 0, stream>>>(x, W1l, W1r, W2l, W2r, xb, wc1, wc2);

    // Layer 1: [XL | XR] = x @ [W1l;W1r]^T   (M=10000, NT=256, K=512)
    {
        dim3 grid(256 / 64, (N_NODES + 127) / 128);
        gemm_mfma<32, IN_DIM, 256, HID><<<grid, 256, 0, stream>>>(xb, wc1, XL, XR, N_NODES);
    }

    // h = relu(mean_agg(XL) + XR + b1) -> bf16 hb
    gather_combine<HID, true, ushort><<<(N_NODES + 3) / 4, 256, 0, stream>>>(
        XL, XR, b1, offs, cnt, bsrc, hb);

    // Layer 2: [HL | HR] = h @ [W2l;W2r]^T   (M=10000, NT=128, K=128)
    {
        dim3 grid(128 / 64, (N_NODES + 63) / 64);
        gemm_mfma<16, HID, 128, OUT_DIM><<<grid, 256, 0, stream>>>(hb, wc2, HL, HR, N_NODES);
    }

    // out = mean_agg(HL) + HR + b2
    gather_combine<OUT_DIM, false, float><<<(N_NODES + 3) / 4, 256, 0, stream>>>(
        HL, HR, b2, offs, cnt, bsrc, out);
}

// Round 4
// 115.713 us; speedup vs baseline: 4.9885x; 1.1011x over previous
//
#include <hip/hip_runtime.h>

#define N_NODES 10000
#define N_EDGES 160000
#define IN_DIM 512
#define HID 128
#define OUT_DIM 64

typedef __attribute__((ext_vector_type(8))) short bf16x8;
typedef __attribute__((ext_vector_type(4))) float f32x4;

__device__ inline ushort f2b(float f) {
    unsigned u = __float_as_uint(f);
    u += 0x7fff + ((u >> 16) & 1);   // round-to-nearest-even
    return (ushort)(u >> 16);
}

// ---------------------------------------------------------------------------
// Zero a small int buffer (replaces pathological hipMemsetAsync fill)
// ---------------------------------------------------------------------------
__global__ void zero_ints(int* __restrict__ p, int n) {
    int i = blockIdx.x * blockDim.x + threadIdx.x;
    if (i < n) p[i] = 0;
}

// ---------------------------------------------------------------------------
// One-shot fp32 -> bf16 conversion of x, W1l|W1r, W2l|W2r (float4 per thread)
// ---------------------------------------------------------------------------
#define XC   (N_NODES * IN_DIM / 4)          // 1,280,000
#define W1C  (HID * IN_DIM / 4)              // 16,384
#define W2C  (OUT_DIM * HID / 4)             // 2,048
#define SEG1 (XC)
#define SEG2 (SEG1 + W1C)
#define SEG3 (SEG2 + W1C)
#define SEG4 (SEG3 + W2C)
#define SEG5 (SEG4 + W2C)

__global__ void convert_all(const float* __restrict__ x,
                            const float* __restrict__ w1l, const float* __restrict__ w1r,
                            const float* __restrict__ w2l, const float* __restrict__ w2r,
                            ushort* __restrict__ xb, ushort* __restrict__ wc1,
                            ushort* __restrict__ wc2) {
    int i = blockIdx.x * blockDim.x + threadIdx.x;
    const float* src; ushort* dst; int off;
    if      (i < SEG1) { src = x;   dst = xb;                 off = i; }
    else if (i < SEG2) { src = w1l; dst = wc1;                off = i - SEG1; }
    else if (i < SEG3) { src = w1r; dst = wc1 + HID * IN_DIM; off = i - SEG2; }
    else if (i < SEG4) { src = w2l; dst = wc2;                off = i - SEG3; }
    else if (i < SEG5) { src = w2r; dst = wc2 + OUT_DIM * HID; off = i - SEG4; }
    else return;
    float4 v = *reinterpret_cast<const float4*>(src + (size_t)off * 4);
    ushort4 o = make_ushort4(f2b(v.x), f2b(v.y), f2b(v.z), f2b(v.w));
    *reinterpret_cast<ushort4*>(dst + (size_t)off * 4) = o;
}

// ---------------------------------------------------------------------------
// bf16 MFMA GEMM:  C[M, NT] = A[M,K] * B[NT,K]^T, split-stored into C0|C1 at
// column HALF. 256 threads = 4 waves; wave w owns rows [w*WROWS, (w+1)*WROWS).
// LDS tiles XOR-swizzled in 16B chunks: conflict-free writes & frag reads.
// ---------------------------------------------------------------------------
template <int WROWS, int K, int NT, int HALF>
__global__ __launch_bounds__(256) void gemm_mfma(const ushort* __restrict__ A,
                                                 const ushort* __restrict__ B,
                                                 float* __restrict__ C0,
                                                 float* __restrict__ C1, int M) {
    constexpr int BM = 4 * WROWS;
    constexpr int RF = WROWS / 16;
    __shared__ __align__(16) ushort Asm[BM * 32];
    __shared__ __align__(16) ushort Bsm[64 * 32];

    const int t    = threadIdx.x;
    const int lane = t & 63;
    const int w    = t >> 6;
    const int m0   = blockIdx.y * BM;
    const int n0   = blockIdx.x * 64;
    const int kch  = lane >> 4;      // k-chunk group for fragments
    const int lrow = lane & 15;

    f32x4 acc[RF][4] = {};

    for (int k0 = 0; k0 < K; k0 += 32) {
        // stage A tile (BM x 32)
        #pragma unroll
        for (int c = t; c < BM * 4; c += 256) {
            int row = c >> 2, kc = c & 3;
            int m = m0 + row;
            uint4 v = make_uint4(0u, 0u, 0u, 0u);
            if (m < M)
                v = *reinterpret_cast<const uint4*>(&A[(size_t)m * K + k0 + kc * 8]);
            *reinterpret_cast<uint4*>(&Asm[row * 32 + ((kc ^ (row & 3)) << 3)]) = v;
        }
        // stage B tile (64 x 32)
        {
            int row = t >> 2, kc = t & 3;
            uint4 v = *reinterpret_cast<const uint4*>(&B[(size_t)(n0 + row) * K + k0 + kc * 8]);
            *reinterpret_cast<uint4*>(&Bsm[row * 32 + ((kc ^ (row & 3)) << 3)]) = v;
        }
        __syncthreads();

        bf16x8 afr[RF], bfr[4];
        #pragma unroll
        for (int rf = 0; rf < RF; ++rf) {
            int row = w * WROWS + rf * 16 + lrow;
            afr[rf] = *reinterpret_cast<const bf16x8*>(&Asm[row * 32 + ((kch ^ (row & 3)) << 3)]);
        }
        #pragma unroll
        for (int cf = 0; cf < 4; ++cf) {
            int row = cf * 16 + lrow;
            bfr[cf] = *reinterpret_cast<const bf16x8*>(&Bsm[row * 32 + ((kch ^ (row & 3)) << 3)]);
        }
        #pragma unroll
        for (int rf = 0; rf < RF; ++rf)
            #pragma unroll
            for (int cf = 0; cf < 4; ++cf)
                acc[rf][cf] = __builtin_amdgcn_mfma_f32_16x16x32_bf16(
                    afr[rf], bfr[cf], acc[rf][cf], 0, 0, 0);
        __syncthreads();
    }

    // epilogue: C layout col = lane&15, row = (lane>>4)*4 + j  [m89]
    #pragma unroll
    for (int rf = 0; rf < RF; ++rf) {
        int baserow = m0 + w * WROWS + rf * 16 + (lane >> 4) * 4;
        #pragma unroll
        for (int cf = 0; cf < 4; ++cf) {
            int col = n0 + cf * 16 + lrow;
            float* Cp; int c2;
            if (col < HALF) { Cp = C0; c2 = col; }
            else            { Cp = C1; c2 = col - HALF; }
            #pragma unroll
            for (int j = 0; j < 4; ++j) {
                int row = baserow + j;
                if (row < M) Cp[(size_t)row * HALF + c2] = acc[rf][cf][j];
            }
        }
    }
}

// ---------------------------------------------------------------------------
// CSR build: histogram, fast single-block scan, bucket fill
// ---------------------------------------------------------------------------
__global__ void count_edges(const int* __restrict__ dst, int* __restrict__ cnt) {
    int e = blockIdx.x * blockDim.x + threadIdx.x;
    if (e < N_EDGES) atomicAdd(&cnt[dst[e]], 1);
}

// 1024 threads; each owns PER contiguous counts. Wave shfl-scan + one LDS
// cross-wave scan; 2 barriers total.
__global__ __launch_bounds__(1024) void scan_offsets(const int* __restrict__ cnt,
                                                     int* __restrict__ offs) {
    constexpr int PER = (N_NODES + 1023) / 1024;  // 10
    __shared__ int wsum[16];
    int t = threadIdx.x;
    int base = t * PER;
    int loc[PER];
    int s = 0;
    #pragma unroll
    for (int j = 0; j < PER; ++j) {
        int i = base + j;
        int v = (i < N_NODES) ? cnt[i] : 0;
        loc[j] = s;                 // exclusive prefix within thread
        s += v;
    }
    int lane = t & 63, wid = t >> 6;
    int pre = s;                    // becomes inclusive wave prefix
    #pragma unroll
    for (int d = 1; d < 64; d <<= 1) {
        int u = __shfl_up(pre, d, 64);
        if (lane >= d) pre += u;
    }
    if (lane == 63) wsum[wid] = pre;
    __syncthreads();
    if (wid == 0 && lane < 16) {
        int v = wsum[lane];
        #pragma unroll
        for (int d = 1; d < 16; d <<= 1) {
            int u = __shfl_up(v, d, 64);
            if (lane >= d) v += u;
        }
        wsum[lane] = v;             // inclusive wave sums
    }
    __syncthreads();
    int wbase = (wid > 0) ? wsum[wid - 1] : 0;
    int tbase = wbase + pre - s;    // exclusive prefix for this thread
    #pragma unroll
    for (int j = 0; j < PER; ++j) {
        int i = base + j;
        if (i < N_NODES) offs[i] = tbase + loc[j];
    }
}

__global__ void fill_buckets(const int* __restrict__ src, const int* __restrict__ dst,
                             const int* __restrict__ offs, int* __restrict__ fill,
                             int* __restrict__ bsrc) {
    int e = blockIdx.x * blockDim.x + threadIdx.x;
    if (e >= N_EDGES) return;
    int d = dst[e];
    int pos = offs[d] + atomicAdd(&fill[d], 1);
    bsrc[pos] = src[e];
}

// ---------------------------------------------------------------------------
// Fused mean-aggregate + self + bias (+relu): one wave per node.
// ---------------------------------------------------------------------------
template <int D, bool RELU, typename OT>
__global__ __launch_bounds__(256) void gather_combine(
    const float* __restrict__ V, const float* __restrict__ xr,
    const float* __restrict__ b, const int* __restrict__ offs,
    const int* __restrict__ cnt, const int* __restrict__ bsrc,
    OT* __restrict__ out) {
    constexpr int LPF = D / 64;
    int wave = threadIdx.x >> 6;
    int lane = threadIdx.x & 63;
    int n = blockIdx.x * 4 + wave;
    if (n >= N_NODES) return;

    int beg = offs[n];
    int deg = cnt[n];
    float acc[LPF] = {};
    for (int i = beg; i < beg + deg; ++i) {
        int s = bsrc[i];                      // wave-uniform
        const float* p = &V[(size_t)s * D + lane * LPF];
        #pragma unroll
        for (int j = 0; j < LPF; ++j) acc[j] += p[j];
    }
    float inv = (deg > 0) ? (1.0f / (float)deg) : 0.0f;
    #pragma unroll
    for (int j = 0; j < LPF; ++j) {
        int f = lane * LPF + j;
        float v = acc[j] * inv + xr[(size_t)n * D + f] + b[f];
        if (RELU) v = fmaxf(v, 0.0f);
        if constexpr (sizeof(OT) == 2) out[(size_t)n * D + f] = (OT)f2b(v);
        else                           out[(size_t)n * D + f] = v;
    }
}

// ---------------------------------------------------------------------------
extern "C" void kernel_launch(void* const* d_in, const int* in_sizes, int n_in,
                              void* d_out, int out_size, void* d_ws, size_t ws_size,
                              hipStream_t stream) {
    const float* x   = (const float*)d_in[0];
    const int*   ei  = (const int*)d_in[1];
    const int*   src = ei;
    const int*   dst = ei + N_EDGES;
    const float* W1l = (const float*)d_in[2];
    const float* W1r = (const float*)d_in[3];
    const float* b1  = (const float*)d_in[4];
    const float* W2l = (const float*)d_in[5];
    const float* W2r = (const float*)d_in[6];
    const float* b2  = (const float*)d_in[7];
    float*       out = (float*)d_out;

    // Workspace layout
    int* cnt  = (int*)d_ws;                       // N
    int* fill = cnt + N_NODES;                    // N
    int* offs = fill + N_NODES;                   // N
    int* bsrc = offs + N_NODES;                   // E
    ushort* xb  = (ushort*)(bsrc + N_EDGES);      // N*512 bf16
    ushort* wc1 = xb + (size_t)N_NODES * IN_DIM;  // 256*512 bf16
    ushort* wc2 = wc1 + (size_t)2 * HID * IN_DIM; // 128*128 bf16
    float* XL   = (float*)(wc2 + 2 * OUT_DIM * HID);  // N*128
    float* XR   = XL + (size_t)N_NODES * HID;         // N*128
    // After layer-1 gather, xb region is dead; reuse it for h/HL/HR.
    ushort* hb = xb;                                        // N*128 bf16
    float* HL  = (float*)(hb + (size_t)N_NODES * HID);      // N*64
    float* HR  = HL + (size_t)N_NODES * OUT_DIM;            // N*64

    // zero cnt+fill (custom kernel; hipMemsetAsync's fill dispatch cost 44us)
    zero_ints<<<(2 * N_NODES + 255) / 256, 256, 0, stream>>>(cnt, 2 * N_NODES);

    // CSR build (by dst)
    count_edges<<<(N_EDGES + 255) / 256, 256, 0, stream>>>(dst, cnt);
    scan_offsets<<<1, 1024, 0, stream>>>(cnt, offs);
    fill_buckets<<<(N_EDGES + 255) / 256, 256, 0, stream>>>(src, dst, offs, fill, bsrc);

    // fp32 -> bf16 (x + all weights)
    convert_all<<<(SEG5 + 255) / 256, 256, 0, stream>>>(x, W1l, W1r, W2l, W2r, xb, wc1, wc2);

    // Layer 1: [XL | XR] = x @ [W1l;W1r]^T   (M=10000, NT=256, K=512)
    {
        dim3 grid(256 / 64, (N_NODES + 127) / 128);
        gemm_mfma<32, IN_DIM, 256, HID><<<grid, 256, 0, stream>>>(xb, wc1, XL, XR, N_NODES);
    }

    // h = relu(mean_agg(XL) + XR + b1) -> bf16 hb
    gather_combine<HID, true, ushort><<<(N_NODES + 3) / 4, 256, 0, stream>>>(
        XL, XR, b1, offs, cnt, bsrc, hb);

    // Layer 2: [HL | HR] = h @ [W2l;W2r]^T   (M=10000, NT=128, K=128)
    {
        dim3 grid(128 / 64, (N_NODES + 63) / 64);
        gemm_mfma<16, HID, 128, OUT_DIM><<<grid, 256, 0, stream>>>(hb, wc2, HL, HR, N_NODES);
    }

    // out = mean_agg(HL) + HR + b2
    gather_combine<OUT_DIM, false, float><<<(N_NODES + 3) / 4, 256, 0, stream>>>(
        HL, HR, b2, offs, cnt, bsrc, out);
}

// Round 5
// 85.984 us; speedup vs baseline: 6.7133x; 1.3458x over previous
//
#include <hip/hip_runtime.h>

#define N_NODES 10000
#define N_EDGES 160000
#define IN_DIM 512
#define HID 128
#define OUT_DIM 64

typedef __attribute__((ext_vector_type(8))) short bf16x8;
typedef __attribute__((ext_vector_type(4))) float f32x4;

__device__ inline ushort f2b(float f) {
    unsigned u = __float_as_uint(f);
    u += 0x7fff + ((u >> 16) & 1);   // round-to-nearest-even
    return (ushort)(u >> 16);
}
__device__ inline uint pack2(float a, float b) {
    return (uint)f2b(a) | ((uint)f2b(b) << 16);
}
__device__ inline float blo(uint u) { return __uint_as_float(u << 16); }
__device__ inline float bhi(uint u) { return __uint_as_float(u & 0xffff0000u); }

// ---------------------------------------------------------------------------
// prep: zero cnt+fill (int4) and convert W1/W2 -> bf16 (float4 chunks)
// ---------------------------------------------------------------------------
#define ZCH 5000                      // 20000 ints as int4
#define W1CH (HID * IN_DIM / 4)       // 16384 float4 chunks per W1 matrix
#define W2CH (OUT_DIM * HID / 4)      // 2048 per W2 matrix
#define PREP_TOT (ZCH + 2 * W1CH + 2 * W2CH)

__global__ void prep(int* __restrict__ zp,
                     const float* __restrict__ w1l, const float* __restrict__ w1r,
                     const float* __restrict__ w2l, const float* __restrict__ w2r,
                     ushort* __restrict__ wc1, ushort* __restrict__ wc2) {
    int i = blockIdx.x * blockDim.x + threadIdx.x;
    if (i < ZCH) { ((int4*)zp)[i] = make_int4(0, 0, 0, 0); return; }
    i -= ZCH;
    const float* src; ushort* dst;
    if      (i < W1CH)     { src = w1l + (size_t)i * 4;            dst = wc1 + (size_t)i * 4; }
    else if (i < 2 * W1CH) { int j = i - W1CH; src = w1r + (size_t)j * 4; dst = wc1 + HID * IN_DIM + (size_t)j * 4; }
    else if (i < 2 * W1CH + W2CH) { int j = i - 2 * W1CH; src = w2l + (size_t)j * 4; dst = wc2 + (size_t)j * 4; }
    else if (i < 2 * W1CH + 2 * W2CH) { int j = i - 2 * W1CH - W2CH; src = w2r + (size_t)j * 4; dst = wc2 + OUT_DIM * HID + (size_t)j * 4; }
    else return;
    float4 v = *reinterpret_cast<const float4*>(src);
    ushort4 o = make_ushort4(f2b(v.x), f2b(v.y), f2b(v.z), f2b(v.w));
    *reinterpret_cast<ushort4*>(dst) = o;
}

// ---------------------------------------------------------------------------
// bf16 MFMA GEMM, BM=64 BN=64 BK=64, 4 waves (wave w owns rows w*16..w*16+15).
// A source is f32 (converted during staging) or bf16. B is pre-converted bf16
// [NT x K]. Output split: cols < HALF -> C0 (bf16), cols >= HALF -> C1 (f32).
// LDS rows of 8 16B-chunks, XOR-swizzled: chunk' = chunk ^ (row&7).
// ---------------------------------------------------------------------------
template <typename AT, int K, int NT, int HALF>
__global__ __launch_bounds__(256) void gemm_mfma(const AT* __restrict__ A,
                                                 const ushort* __restrict__ B,
                                                 ushort* __restrict__ C0,
                                                 float* __restrict__ C1, int M) {
    __shared__ __align__(16) ushort Asm[64 * 64];
    __shared__ __align__(16) ushort Bsm[64 * 64];

    const int t    = threadIdx.x;
    const int lane = t & 63;
    const int w    = t >> 6;
    const int m0   = blockIdx.y * 64;
    const int n0   = blockIdx.x * 64;
    const int kch  = lane >> 4;      // 0..3
    const int lrow = lane & 15;

    f32x4 acc[4] = {};

    for (int k0 = 0; k0 < K; k0 += 64) {
        // stage A (64 rows x 64 k)
        #pragma unroll
        for (int ch = t; ch < 64 * 8; ch += 256) {
            int row = ch >> 3, c = ch & 7;
            int m = m0 + row;
            uint4 o = make_uint4(0u, 0u, 0u, 0u);
            if (m < M) {
                if constexpr (sizeof(AT) == 4) {
                    const float* p = (const float*)A + (size_t)m * K + k0 + c * 8;
                    float4 v0 = reinterpret_cast<const float4*>(p)[0];
                    float4 v1 = reinterpret_cast<const float4*>(p)[1];
                    o.x = pack2(v0.x, v0.y); o.y = pack2(v0.z, v0.w);
                    o.z = pack2(v1.x, v1.y); o.w = pack2(v1.z, v1.w);
                } else {
                    o = *reinterpret_cast<const uint4*>((const ushort*)A + (size_t)m * K + k0 + c * 8);
                }
            }
            *reinterpret_cast<uint4*>(&Asm[row * 64 + ((c ^ (row & 7)) << 3)]) = o;
        }
        // stage B (64 rows x 64 k), rows always in range
        #pragma unroll
        for (int ch = t; ch < 64 * 8; ch += 256) {
            int row = ch >> 3, c = ch & 7;
            uint4 o = *reinterpret_cast<const uint4*>(&B[(size_t)(n0 + row) * K + k0 + c * 8]);
            *reinterpret_cast<uint4*>(&Bsm[row * 64 + ((c ^ (row & 7)) << 3)]) = o;
        }
        __syncthreads();

        bf16x8 afr[2], bfr[2][4];
        const int arow = w * 16 + lrow;
        #pragma unroll
        for (int h = 0; h < 2; ++h) {
            int c = h * 4 + kch;
            afr[h] = *reinterpret_cast<const bf16x8*>(&Asm[arow * 64 + ((c ^ (arow & 7)) << 3)]);
            #pragma unroll
            for (int cf = 0; cf < 4; ++cf) {
                int brow = cf * 16 + lrow;
                bfr[h][cf] = *reinterpret_cast<const bf16x8*>(&Bsm[brow * 64 + ((c ^ (brow & 7)) << 3)]);
            }
        }
        #pragma unroll
        for (int h = 0; h < 2; ++h)
            #pragma unroll
            for (int cf = 0; cf < 4; ++cf)
                acc[cf] = __builtin_amdgcn_mfma_f32_16x16x32_bf16(
                    afr[h], bfr[h][cf], acc[cf], 0, 0, 0);
        __syncthreads();
    }

    // epilogue: col = lane&15 (+cf*16), row = (lane>>4)*4 + j   [m89 layout]
    #pragma unroll
    for (int cf = 0; cf < 4; ++cf) {
        int col = n0 + cf * 16 + lrow;
        #pragma unroll
        for (int j = 0; j < 4; ++j) {
            int row = m0 + w * 16 + (lane >> 4) * 4 + j;
            if (row >= M) continue;
            if (col < HALF) C0[(size_t)row * HALF + col] = f2b(acc[cf][j]);
            else            C1[(size_t)row * (NT - HALF) + col - HALF] = acc[cf][j];
        }
    }
}

// ---------------------------------------------------------------------------
// CSR build: histogram, single-block scan, bucket fill
// ---------------------------------------------------------------------------
__global__ void count_edges(const int* __restrict__ dst, int* __restrict__ cnt) {
    int e = blockIdx.x * blockDim.x + threadIdx.x;
    if (e < N_EDGES) atomicAdd(&cnt[dst[e]], 1);
}

__global__ __launch_bounds__(1024) void scan_offsets(const int* __restrict__ cnt,
                                                     int* __restrict__ offs) {
    constexpr int PER = (N_NODES + 1023) / 1024;  // 10
    __shared__ int wsum[16];
    int t = threadIdx.x;
    int base = t * PER;
    int loc[PER];
    int s = 0;
    #pragma unroll
    for (int j = 0; j < PER; ++j) {
        int i = base + j;
        int v = (i < N_NODES) ? cnt[i] : 0;
        loc[j] = s;
        s += v;
    }
    int lane = t & 63, wid = t >> 6;
    int pre = s;
    #pragma unroll
    for (int d = 1; d < 64; d <<= 1) {
        int u = __shfl_up(pre, d, 64);
        if (lane >= d) pre += u;
    }
    if (lane == 63) wsum[wid] = pre;
    __syncthreads();
    if (wid == 0 && lane < 16) {
        int v = wsum[lane];
        #pragma unroll
        for (int d = 1; d < 16; d <<= 1) {
            int u = __shfl_up(v, d, 64);
            if (lane >= d) v += u;
        }
        wsum[lane] = v;
    }
    __syncthreads();
    int wbase = (wid > 0) ? wsum[wid - 1] : 0;
    int tbase = wbase + pre - s;
    #pragma unroll
    for (int j = 0; j < PER; ++j) {
        int i = base + j;
        if (i < N_NODES) offs[i] = tbase + loc[j];
    }
}

__global__ void fill_buckets(const int* __restrict__ src, const int* __restrict__ dst,
                             const int* __restrict__ offs, int* __restrict__ fill,
                             int* __restrict__ bsrc) {
    int e = blockIdx.x * blockDim.x + threadIdx.x;
    if (e >= N_EDGES) return;
    int d = dst[e];
    int pos = offs[d] + atomicAdd(&fill[d], 1);
    bsrc[pos] = src[e];
}

// ---------------------------------------------------------------------------
// Fused mean-aggregate + self + bias (+relu). One wave per node, bf16 V table,
// edge loop unrolled x4 for MLP.
//   D=128: lane owns 2 features (uint load), bf16 out (hb)
//   D=64 : lane owns 1 feature (ushort load), f32 out
// ---------------------------------------------------------------------------
template <int D, bool RELU, typename OT>
__global__ __launch_bounds__(256) void gather_combine(
    const ushort* __restrict__ V, const float* __restrict__ xr,
    const float* __restrict__ b, const int* __restrict__ offs,
    const int* __restrict__ cnt, const int* __restrict__ bsrc,
    OT* __restrict__ out) {
    int wave = threadIdx.x >> 6;
    int lane = threadIdx.x & 63;
    int n = blockIdx.x * 4 + wave;
    if (n >= N_NODES) return;

    int beg = offs[n];
    int deg = cnt[n];
    int end = beg + deg;

    float a0 = 0.f, a1 = 0.f;
    int i = beg;
    if constexpr (D == 128) {
        for (; i + 4 <= end; i += 4) {
            int s0 = bsrc[i], s1 = bsrc[i + 1], s2 = bsrc[i + 2], s3 = bsrc[i + 3];
            uint u0 = *(const uint*)(V + (size_t)s0 * 128 + lane * 2);
            uint u1 = *(const uint*)(V + (size_t)s1 * 128 + lane * 2);
            uint u2 = *(const uint*)(V + (size_t)s2 * 128 + lane * 2);
            uint u3 = *(const uint*)(V + (size_t)s3 * 128 + lane * 2);
            a0 += blo(u0) + blo(u1) + blo(u2) + blo(u3);
            a1 += bhi(u0) + bhi(u1) + bhi(u2) + bhi(u3);
        }
        for (; i < end; ++i) {
            int s = bsrc[i];
            uint u = *(const uint*)(V + (size_t)s * 128 + lane * 2);
            a0 += blo(u); a1 += bhi(u);
        }
    } else {
        for (; i + 4 <= end; i += 4) {
            int s0 = bsrc[i], s1 = bsrc[i + 1], s2 = bsrc[i + 2], s3 = bsrc[i + 3];
            float v0 = blo((uint)V[(size_t)s0 * 64 + lane]);
            float v1 = blo((uint)V[(size_t)s1 * 64 + lane]);
            float v2 = blo((uint)V[(size_t)s2 * 64 + lane]);
            float v3 = blo((uint)V[(size_t)s3 * 64 + lane]);
            a0 += v0 + v1 + v2 + v3;
        }
        for (; i < end; ++i) {
            int s = bsrc[i];
            a0 += blo((uint)V[(size_t)s * 64 + lane]);
        }
    }

    float inv = (deg > 0) ? (1.0f / (float)deg) : 0.0f;
    if constexpr (D == 128) {
        float2 xv = *(const float2*)&xr[(size_t)n * 128 + lane * 2];
        float v0 = a0 * inv + xv.x + b[lane * 2];
        float v1 = a1 * inv + xv.y + b[lane * 2 + 1];
        if (RELU) { v0 = fmaxf(v0, 0.f); v1 = fmaxf(v1, 0.f); }
        *(uint*)((ushort*)out + (size_t)n * 128 + lane * 2) = pack2(v0, v1);
    } else {
        float v0 = a0 * inv + xr[(size_t)n * 64 + lane] + b[lane];
        if (RELU) v0 = fmaxf(v0, 0.f);
        ((float*)out)[(size_t)n * 64 + lane] = v0;
    }
}

// ---------------------------------------------------------------------------
extern "C" void kernel_launch(void* const* d_in, const int* in_sizes, int n_in,
                              void* d_out, int out_size, void* d_ws, size_t ws_size,
                              hipStream_t stream) {
    const float* x   = (const float*)d_in[0];
    const int*   ei  = (const int*)d_in[1];
    const int*   src = ei;
    const int*   dst = ei + N_EDGES;
    const float* W1l = (const float*)d_in[2];
    const float* W1r = (const float*)d_in[3];
    const float* b1  = (const float*)d_in[4];
    const float* W2l = (const float*)d_in[5];
    const float* W2r = (const float*)d_in[6];
    const float* b2  = (const float*)d_in[7];
    float*       out = (float*)d_out;

    // Workspace layout (16B-aligned sections)
    int* cnt  = (int*)d_ws;                         // N
    int* fill = cnt + N_NODES;                      // N
    int* offs = fill + N_NODES;                     // N
    int* bsrc = offs + N_NODES;                     // E
    ushort* wc1 = (ushort*)(bsrc + N_EDGES);        // 2*128*512
    ushort* wc2 = wc1 + (size_t)2 * HID * IN_DIM;   // 2*64*128
    ushort* XL  = wc2 + (size_t)2 * OUT_DIM * HID;  // N*128 bf16
    float*  XR  = (float*)(XL + (size_t)N_NODES * HID);   // N*128 f32
    ushort* hb  = (ushort*)(XR + (size_t)N_NODES * HID);  // N*128 bf16
    ushort* HL  = hb + (size_t)N_NODES * HID;             // N*64 bf16
    float*  HR  = (float*)(HL + (size_t)N_NODES * OUT_DIM); // N*64 f32

    // prep: zero cnt+fill, convert weights to bf16
    prep<<<(PREP_TOT + 255) / 256, 256, 0, stream>>>(cnt, W1l, W1r, W2l, W2r, wc1, wc2);

    // CSR build (by dst)
    count_edges<<<(N_EDGES + 255) / 256, 256, 0, stream>>>(dst, cnt);
    scan_offsets<<<1, 1024, 0, stream>>>(cnt, offs);
    fill_buckets<<<(N_EDGES + 255) / 256, 256, 0, stream>>>(src, dst, offs, fill, bsrc);

    // Layer 1: [XL(bf16) | XR(f32)] = x @ [W1l;W1r]^T  (M=10000, NT=256, K=512)
    {
        dim3 grid(256 / 64, (N_NODES + 63) / 64);
        gemm_mfma<float, IN_DIM, 256, HID><<<grid, 256, 0, stream>>>(x, wc1, XL, XR, N_NODES);
    }

    // h = relu(mean_agg(XL) + XR + b1) -> bf16 hb
    gather_combine<HID, true, ushort><<<(N_NODES + 3) / 4, 256, 0, stream>>>(
        XL, XR, b1, offs, cnt, bsrc, hb);

    // Layer 2: [HL(bf16) | HR(f32)] = h @ [W2l;W2r]^T  (M=10000, NT=128, K=128)
    {
        dim3 grid(128 / 64, (N_NODES + 63) / 64);
        gemm_mfma<ushort, HID, 128, OUT_DIM><<<grid, 256, 0, stream>>>(hb, wc2, HL, HR, N_NODES);
    }

    // out = mean_agg(HL) + HR + b2
    gather_combine<OUT_DIM, false, float><<<(N_NODES + 3) / 4, 256, 0, stream>>>(
        HL, HR, b2, offs, cnt, bsrc, out);
}